// Round 4
// baseline (239.268 us; speedup 1.0000x reference)
//
#include <hip/hip_runtime.h>
#include <math.h>

typedef __attribute__((ext_vector_type(8))) short bf16x8;
typedef __attribute__((ext_vector_type(4))) float f32x4;

static __device__ __forceinline__ unsigned short f2b(float x) {
  unsigned int u = __float_as_uint(x);
  u += 0x7FFFu + ((u >> 16) & 1u);  // round-to-nearest-even
  return (unsigned short)(u >> 16);
}

// ---------------- prep kernel (weights + msq merged: one launch) ----------------
// W1 [256][512] -> W1T bf16 [512][256]; W2 [512][256] -> W2T bf16 [256][512];
// memory [50][256] -> memB bf16 [64][256] (zero-padded rows); msq[64] fp32.
__global__ void prep_weights(const float* __restrict__ W1,
                             const float* __restrict__ W2,
                             const float* __restrict__ mem,
                             unsigned short* __restrict__ W1T,
                             unsigned short* __restrict__ W2T,
                             unsigned short* __restrict__ memB,
                             float* __restrict__ msq) {
  int i = blockIdx.x * 256 + threadIdx.x;
  if (i < 131072) {
    int k = i >> 9, n = i & 511;            // W1[k][n]
    W1T[n * 256 + k] = f2b(W1[i]);
  } else if (i < 262144) {
    int j = i - 131072;
    int k = j >> 8, n = j & 255;            // W2[k][n]
    W2T[n * 512 + k] = f2b(W2[j]);
  } else if (i < 278528) {
    int j = i - 262144;
    int r = j >> 8;
    memB[j] = (r < 50) ? f2b(mem[j]) : (unsigned short)0;
  } else {
    // block 1088: msq. 4 threads per memory row, 64 elems each.
    int t = threadIdx.x;
    int r = t >> 2, c0 = (t & 3) * 64;
    float s = 0.f;
    if (r < 50) {
      for (int c = 0; c < 64; ++c) {
        float v = mem[r * 256 + c0 + c];
        s += v * v;
      }
    }
    s += __shfl_xor(s, 1, 64);
    s += __shfl_xor(s, 2, 64);
    if ((t & 3) == 0) msq[r] = (r < 50) ? s : 1e30f;
  }
}

// ---------------- fused main kernel ----------------
// 32 tokens per block, 2048 blocks. LDS = 20480 B exactly:
//   Xs: bytes [0, 16384)     — swizzled dense [32][256] bf16, row stride 512 B
//   Hs: bytes [16384, 20480) — swizzled dense [32][64] bf16, row stride 128 B
// XOR swizzle: byte ^= (row&7)<<4. All wave-wide ds accesses are uniform across
// bank slots (floor-rate). Aliases (sequential lifetimes, barrier-separated):
//   red (480 f32)   aliases Hs  (Hs dead after last GEMM2)
//   distS [32][53]  aliases Xs  (Xs/feats dead after phase-3 reads)
// Occupancy: LDS allows >=6 blocks/CU even if usable LDS is only 128 KiB;
// VGPR cap 128 via __launch_bounds__(256,4) -> no spill (natural ~100),
// actual blocks/CU = min(512/VGPR, LDS limit).
#define DPitch 53  // odd stride -> phase-4 row scans conflict-free

#define SWZ(b, r) ((b) ^ (((r) & 7) << 4))

__global__ __launch_bounds__(256, 4) void fused_main(
    const float* __restrict__ X, const float* __restrict__ b1v,
    const float* __restrict__ b2v, const float* __restrict__ gammav,
    const float* __restrict__ betav, const unsigned short* __restrict__ W1T,
    const unsigned short* __restrict__ W2T,
    const unsigned short* __restrict__ memB, const float* __restrict__ msq,
    float* __restrict__ out) {
  __shared__ __align__(16) char smem[20480];
  float* distS = (float*)smem;             // aliases Xs, used phase 3b..4
  float* red = (float*)(smem + 16384);     // aliases Hs, used phase 2a..3
  float* psum   = red;        // [4][32]
  float* psumsq = red + 128;  // [4][32]
  float* fsqp   = red + 256;  // [4][32]
  float* muS    = red + 384;  // [32]
  float* rstdS  = red + 416;  // [32]
  float* fsqS   = red + 448;  // [32]

  const char* W1Tc = (const char*)W1T;  // row stride 512 B
  const char* W2Tc = (const char*)W2T;  // row stride 1024 B

  const int tid = threadIdx.x;
  const int wid = tid >> 6;
  const int lane = tid & 63;
  const int l16 = lane & 15;
  const int quad = lane >> 4;

  // ---- Phase 0: stage X tile [32][256] fp32 -> swizzled LDS bf16 ----
  const float4* X4 = (const float4*)(X + (size_t)blockIdx.x * 32 * 256);
#pragma unroll
  for (int j = 0; j < 8; ++j) {
    int row = j * 4 + wid;  // each wave fills one full row per j
    float4 v = X4[row * 64 + lane];
    unsigned int p0 = f2b(v.x) | ((unsigned int)f2b(v.y) << 16);
    unsigned int p1 = f2b(v.z) | ((unsigned int)f2b(v.w) << 16);
    *(uint2*)(smem + SWZ(row * 512 + lane * 8, row)) = make_uint2(p0, p1);
  }

  // F^T accumulators: (fcol = wid*64+mt*16+quad*4+reg, token = nt*16+l16), nt:0..1
  f32x4 acc2[4][2];
#pragma unroll
  for (int mt = 0; mt < 4; ++mt) {
    const float4 bb = *(const float4*)(&b2v[wid * 64 + mt * 16 + quad * 4]);
#pragma unroll
    for (int nt = 0; nt < 2; ++nt) {
      acc2[mt][nt][0] = bb.x; acc2[mt][nt][1] = bb.y;
      acc2[mt][nt][2] = bb.z; acc2[mt][nt][3] = bb.w;
    }
  }

  __syncthreads();

  // ---- Phase 1: 8 chunks of 64 hcols: GEMM1 -> relu -> Hs; GEMM2 accumulate ----
  for (int cc = 0; cc < 8; ++cc) {
    // GEMM1: this wave computes 16 hcols x 32 tokens, K = 256
    int hbase = cc * 64 + wid * 16;
    f32x4 acc1[2];
    {
      const float4 bb = *(const float4*)(&b1v[hbase + quad * 4]);
#pragma unroll
      for (int nt = 0; nt < 2; ++nt) {
        acc1[nt][0] = bb.x; acc1[nt][1] = bb.y;
        acc1[nt][2] = bb.z; acc1[nt][3] = bb.w;
      }
    }
#pragma unroll
    for (int kk = 0; kk < 8; ++kk) {
      int kb = kk * 64 + quad * 16;  // byte offset within a 512-B K row
      bf16x8 a = *(const bf16x8*)(W1Tc + (hbase + l16) * 512 + kb);
      bf16x8 b[2];
#pragma unroll
      for (int nt = 0; nt < 2; ++nt) {
        int r = nt * 16 + l16;
        b[nt] = *(const bf16x8*)(smem + SWZ(r * 512 + kb, r));
      }
#pragma unroll
      for (int nt = 0; nt < 2; ++nt)
        acc1[nt] = __builtin_amdgcn_mfma_f32_16x16x32_bf16(a, b[nt], acc1[nt], 0, 0, 0);
    }
    __syncthreads();  // all waves done GEMM2(cc-1) reads of Hs
    // epilogue: relu -> bf16 -> Hs[token][hloc] (4 consecutive hcols/lane)
#pragma unroll
    for (int nt = 0; nt < 2; ++nt) {
      int token = nt * 16 + l16;
      f32x4 v = acc1[nt];
      unsigned int p0 = f2b(fmaxf(v[0], 0.f)) | ((unsigned int)f2b(fmaxf(v[1], 0.f)) << 16);
      unsigned int p1 = f2b(fmaxf(v[2], 0.f)) | ((unsigned int)f2b(fmaxf(v[3], 0.f)) << 16);
      *(uint2*)(smem + 16384 + SWZ(token * 128 + wid * 32 + quad * 8, token)) =
          make_uint2(p0, p1);
    }
    __syncthreads();
    // GEMM2 partial: F^T += W2T[:, cc*64:+64] x Hs   (K = 64)
#pragma unroll
    for (int k2 = 0; k2 < 2; ++k2) {
      bf16x8 a[4], b[2];
#pragma unroll
      for (int mt = 0; mt < 4; ++mt)
        a[mt] = *(const bf16x8*)(W2Tc + (wid * 64 + mt * 16 + l16) * 1024 +
                                 cc * 128 + k2 * 64 + quad * 16);
#pragma unroll
      for (int nt = 0; nt < 2; ++nt) {
        int r = nt * 16 + l16;
        b[nt] = *(const bf16x8*)(smem + 16384 + SWZ(r * 128 + k2 * 64 + quad * 16, r));
      }
#pragma unroll
      for (int mt = 0; mt < 4; ++mt)
#pragma unroll
        for (int nt = 0; nt < 2; ++nt)
          acc2[mt][nt] = __builtin_amdgcn_mfma_f32_16x16x32_bf16(
              a[mt], b[nt], acc2[mt][nt], 0, 0, 0);
    }
  }

  // red aliases Hs: all waves must be done reading Hs (last GEMM2) first.
  __syncthreads();

  // ---- Phase 2a: per-token sum/sumsq for LayerNorm ----
#pragma unroll
  for (int nt = 0; nt < 2; ++nt) {
    float s = 0.f, sq = 0.f;
#pragma unroll
    for (int mt = 0; mt < 4; ++mt)
#pragma unroll
      for (int r = 0; r < 4; ++r) {
        float v = acc2[mt][nt][r];
        s += v; sq += v * v;
      }
    s += __shfl_xor(s, 16, 64); sq += __shfl_xor(sq, 16, 64);
    s += __shfl_xor(s, 32, 64); sq += __shfl_xor(sq, 32, 64);
    if (quad == 0) {
      psum[wid * 32 + nt * 16 + l16] = s;
      psumsq[wid * 32 + nt * 16 + l16] = sq;
    }
  }
  __syncthreads();
  if (tid < 32) {
    float s = psum[tid] + psum[32 + tid] + psum[64 + tid] + psum[96 + tid];
    float sq = psumsq[tid] + psumsq[32 + tid] + psumsq[64 + tid] + psumsq[96 + tid];
    float mu = s * (1.f / 256.f);
    float var = sq * (1.f / 256.f) - mu * mu;
    muS[tid] = mu;
    rstdS[tid] = rsqrtf(var + 1e-5f);
  }
  __syncthreads();

  // ---- Phase 2b: normalize in-register, write feats bf16 back over Xs, fsq ----
  {
    float4 g[4], be[4];
#pragma unroll
    for (int mt = 0; mt < 4; ++mt) {
      g[mt]  = *(const float4*)(&gammav[wid * 64 + mt * 16 + quad * 4]);
      be[mt] = *(const float4*)(&betav[wid * 64 + mt * 16 + quad * 4]);
    }
#pragma unroll
    for (int nt = 0; nt < 2; ++nt) {
      int token = nt * 16 + l16;
      float mu = muS[token], rs = rstdS[token];
      float fs = 0.f;
#pragma unroll
      for (int mt = 0; mt < 4; ++mt) {
        float y0 = (acc2[mt][nt][0] - mu) * rs * g[mt].x + be[mt].x;
        float y1 = (acc2[mt][nt][1] - mu) * rs * g[mt].y + be[mt].y;
        float y2 = (acc2[mt][nt][2] - mu) * rs * g[mt].z + be[mt].z;
        float y3 = (acc2[mt][nt][3] - mu) * rs * g[mt].w + be[mt].w;
        fs += y0 * y0 + y1 * y1 + y2 * y2 + y3 * y3;
        unsigned int p0 = f2b(y0) | ((unsigned int)f2b(y1) << 16);
        unsigned int p1 = f2b(y2) | ((unsigned int)f2b(y3) << 16);
        *(uint2*)(smem + SWZ(token * 512 + wid * 128 + mt * 32 + quad * 8, token)) =
            make_uint2(p0, p1);
      }
      fs += __shfl_xor(fs, 16, 64);
      fs += __shfl_xor(fs, 32, 64);
      if (quad == 0) fsqp[wid * 32 + token] = fs;
    }
  }
  __syncthreads();
  if (tid < 32)
    fsqS[tid] = fsqp[tid] + fsqp[32 + tid] + fsqp[64 + tid] + fsqp[96 + tid];
  __syncthreads();

  // ---- Phase 3: dots GEMM, 4-way wave split ----
  // wave w: token half th = w&1 (16 tokens), memory half mh = w>>1 (32 rows)
  {
    const int th = wid & 1, mh = wid >> 1;
    f32x4 acc3[2];
#pragma unroll
    for (int j = 0; j < 2; ++j) {
      acc3[j][0] = 0.f; acc3[j][1] = 0.f; acc3[j][2] = 0.f; acc3[j][3] = 0.f;
    }
    const int ar = th * 16 + l16;
#pragma unroll
    for (int kk = 0; kk < 8; ++kk) {
      int kb = kk * 64 + quad * 16;
      bf16x8 a = *(const bf16x8*)(smem + SWZ(ar * 512 + kb, ar));
      int k0 = kk * 32 + quad * 8;
#pragma unroll
      for (int j = 0; j < 2; ++j) {
        bf16x8 b = *(const bf16x8*)(memB + (mh * 32 + j * 16 + l16) * 256 + k0);
        acc3[j] = __builtin_amdgcn_mfma_f32_16x16x32_bf16(a, b, acc3[j], 0, 0, 0);
      }
    }
    // distS aliases Xs: every wave must be done with its feats reads above.
    __syncthreads();
    float4 fsq4 = *(const float4*)(&fsqS[th * 16 + quad * 4]);
#pragma unroll
    for (int j = 0; j < 2; ++j) {
      int col = mh * 32 + j * 16 + l16;
      float mq = msq[col];
#pragma unroll
      for (int r = 0; r < 4; ++r) {
        float fv = (r == 0) ? fsq4.x : (r == 1) ? fsq4.y : (r == 2) ? fsq4.z : fsq4.w;
        float d2 = fv + mq - 2.f * acc3[j][r];
        float d = sqrtf(fmaxf(d2, 0.f));
        int row = th * 16 + quad * 4 + r;
        if (col < 50) distS[row * DPitch + col] = d;  // cols >= 50 never read
      }
    }
  }
  __syncthreads();

  // ---- Phase 4: top-5 smallest of 50, mean, sigmoid ----
  if (tid < 32) {
    float b0 = 1e30f, b1 = 1e30f, b2 = 1e30f, b3 = 1e30f, b4 = 1e30f;
    const float* dr = &distS[tid * DPitch];
    for (int j = 0; j < 50; ++j) {
      float v = dr[j];
      b4 = fminf(b4, v);
      float t;
      if (b4 < b3) { t = b3; b3 = b4; b4 = t; }
      if (b3 < b2) { t = b2; b2 = b3; b3 = t; }
      if (b2 < b1) { t = b1; b1 = b2; b2 = t; }
      if (b1 < b0) { t = b0; b0 = b1; b1 = t; }
    }
    float avg = (b0 + b1 + b2 + b3 + b4) * 0.2f;
    float sarg = avg - 1.f;
    out[blockIdx.x * 32 + tid] = 1.f / (1.f + __expf(-sarg));
  }
}

// ---------------- launch ----------------
extern "C" void kernel_launch(void* const* d_in, const int* in_sizes, int n_in,
                              void* d_out, int out_size, void* d_ws, size_t ws_size,
                              hipStream_t stream) {
  const float* X   = (const float*)d_in[0];  // [8*8192][256]
  const float* mem = (const float*)d_in[1];  // [50][256]
  const float* W1  = (const float*)d_in[2];  // [256][512]
  const float* b1  = (const float*)d_in[3];  // [512]
  const float* W2  = (const float*)d_in[4];  // [512][256]
  const float* b2  = (const float*)d_in[5];  // [256]
  const float* g   = (const float*)d_in[6];  // [256]
  const float* be  = (const float*)d_in[7];  // [256]
  float* out = (float*)d_out;                // [65536]

  unsigned short* W1T  = (unsigned short*)d_ws;   // [512][256] bf16
  unsigned short* W2T  = W1T + 131072;            // [256][512] bf16
  unsigned short* memB = W2T + 131072;            // [64][256] bf16
  float* msq = (float*)(memB + 16384);            // [64] fp32

  prep_weights<<<1089, 256, 0, stream>>>(W1, W2, mem, W1T, W2T, memB, msq);
  fused_main<<<2048, 256, 0, stream>>>(X, b1, b2, g, be, W1T, W2T, memB, msq, out);
}

// Round 5
// 189.284 us; speedup vs baseline: 1.2641x; 1.2641x over previous
//
#include <hip/hip_runtime.h>
#include <math.h>

typedef __attribute__((ext_vector_type(8))) short bf16x8;
typedef __attribute__((ext_vector_type(4))) float f32x4;

static __device__ __forceinline__ unsigned short f2b(float x) {
  unsigned int u = __float_as_uint(x);
  u += 0x7FFFu + ((u >> 16) & 1u);  // round-to-nearest-even
  return (unsigned short)(u >> 16);
}

// packed f32x2 -> bf16x2 (RTNE, bit-identical to f2b pair). No builtin on
// gfx950 (m240) -> inline asm. 1 instr replaces ~14.
static __device__ __forceinline__ unsigned int cvtpk(float lo, float hi) {
  unsigned int r;
  asm("v_cvt_pk_bf16_f32 %0, %1, %2" : "=v"(r) : "v"(lo), "v"(hi));
  return r;
}

// ---------------- prep kernel (weights + msq merged: one launch) ----------------
__global__ void prep_weights(const float* __restrict__ W1,
                             const float* __restrict__ W2,
                             const float* __restrict__ mem,
                             unsigned short* __restrict__ W1T,
                             unsigned short* __restrict__ W2T,
                             unsigned short* __restrict__ memB,
                             float* __restrict__ msq) {
  int i = blockIdx.x * 256 + threadIdx.x;
  if (i < 131072) {
    int k = i >> 9, n = i & 511;            // W1[k][n]
    W1T[n * 256 + k] = f2b(W1[i]);
  } else if (i < 262144) {
    int j = i - 131072;
    int k = j >> 8, n = j & 255;            // W2[k][n]
    W2T[n * 512 + k] = f2b(W2[j]);
  } else if (i < 278528) {
    int j = i - 262144;
    int r = j >> 8;
    memB[j] = (r < 50) ? f2b(mem[j]) : (unsigned short)0;
  } else {
    // block 1088: msq. 4 threads per memory row, 64 elems each.
    int t = threadIdx.x;
    int r = t >> 2, c0 = (t & 3) * 64;
    float s = 0.f;
    if (r < 50) {
      for (int c = 0; c < 64; ++c) {
        float v = mem[r * 256 + c0 + c];
        s += v * v;
      }
    }
    s += __shfl_xor(s, 1, 64);
    s += __shfl_xor(s, 2, 64);
    if ((t & 3) == 0) msq[r] = (r < 50) ? s : 1e30f;
  }
}

// ---------------- fused main kernel ----------------
// 64 tokens/block, 1024 blocks. LDS 65536 B:
//   Xs : [0, 32768)      swizzled dense [64][256] bf16 (row 512 B); later feats
//   Hs0: [32768, 49152)  swizzled dense [64][128] bf16 (row 256 B)  } double
//   Hs1: [49152, 65536)                                             } buffer
// XOR swizzle byte ^= (row&7)<<4 — all row-strided accesses hit floor rate.
// Aliases (lifetimes barrier-separated):
//   red (960 f32) aliases Hs0 (Hs0 dead after GEMM2(2))
//   distS [64][53] aliases Xs (feats dead after phase-3 reads)
// Phase-1 pipeline, ONE barrier per 128-hcol chunk:
//   GEMM1(0)->Hs0 | bar | [GEMM2(cc-1) ; GEMM1(cc)->Hs(cc&1) | bar] cc=1..3
//   | GEMM2(3).  GEMM2's W2T loads overlap GEMM1's MFMAs in one window.
#define DPitch 53
#define SWZ(b, r) ((b) ^ (((r) & 7) << 4))

__global__ __launch_bounds__(256, 2) void fused_main(
    const float* __restrict__ X, const float* __restrict__ b1v,
    const float* __restrict__ b2v, const float* __restrict__ gammav,
    const float* __restrict__ betav, const unsigned short* __restrict__ W1T,
    const unsigned short* __restrict__ W2T,
    const unsigned short* __restrict__ memB, const float* __restrict__ msq,
    float* __restrict__ out) {
  __shared__ __align__(16) char smem[65536];
  float* distS = (float*)smem;             // aliases Xs
  float* red = (float*)(smem + 32768);     // aliases Hs0
  float* psum   = red;        // [4][64]
  float* psumsq = red + 256;  // [4][64]
  float* fsqp   = red + 512;  // [4][64]
  float* muS    = red + 768;  // [64]
  float* rstdS  = red + 832;  // [64]
  float* fsqS   = red + 896;  // [64]

  const char* W1Tc = (const char*)W1T;  // row stride 512 B
  const char* W2Tc = (const char*)W2T;  // row stride 1024 B

  const int tid = threadIdx.x;
  const int wid = tid >> 6;
  const int lane = tid & 63;
  const int l16 = lane & 15;
  const int quad = lane >> 4;

  // ---- Phase 0: stage X tile [64][256] fp32 -> swizzled LDS bf16 ----
  const float4* X4 = (const float4*)(X + (size_t)blockIdx.x * 64 * 256);
#pragma unroll
  for (int j = 0; j < 16; ++j) {
    int row = j * 4 + wid;  // each wave fills one full row per j
    float4 v = X4[row * 64 + lane];
    *(uint2*)(smem + SWZ(row * 512 + lane * 8, row)) =
        make_uint2(cvtpk(v.x, v.y), cvtpk(v.z, v.w));
  }

  // F^T accumulators: (fcol = wid*64+mt*16+quad*4+reg, token = nt*16+l16)
  f32x4 acc2[4][4];
#pragma unroll
  for (int mt = 0; mt < 4; ++mt) {
    const float4 bb = *(const float4*)(&b2v[wid * 64 + mt * 16 + quad * 4]);
#pragma unroll
    for (int nt = 0; nt < 4; ++nt) {
      acc2[mt][nt][0] = bb.x; acc2[mt][nt][1] = bb.y;
      acc2[mt][nt][2] = bb.z; acc2[mt][nt][3] = bb.w;
    }
  }

  __syncthreads();

  // ---- Phase 1: software-pipelined chunks (128 hcols each) ----
#pragma unroll
  for (int cc = 0; cc < 4; ++cc) {
    // -- GEMM2(cc-1): F^T += W2T[:, (cc-1)*128:+128] x Hs[(cc-1)&1] --
    if (cc > 0) {
      const char* HsR = smem + 32768 + ((cc - 1) & 1) * 16384;
#pragma unroll
      for (int k2 = 0; k2 < 4; ++k2) {
        bf16x8 a[4], b[4];
#pragma unroll
        for (int mt = 0; mt < 4; ++mt)
          a[mt] = *(const bf16x8*)(W2Tc + (wid * 64 + mt * 16 + l16) * 1024 +
                                   (cc - 1) * 256 + k2 * 64 + quad * 16);
#pragma unroll
        for (int nt = 0; nt < 4; ++nt) {
          int r = nt * 16 + l16;
          b[nt] = *(const bf16x8*)(HsR + SWZ(r * 256 + k2 * 64 + quad * 16, r));
        }
#pragma unroll
        for (int mt = 0; mt < 4; ++mt)
#pragma unroll
          for (int nt = 0; nt < 4; ++nt)
            acc2[mt][nt] = __builtin_amdgcn_mfma_f32_16x16x32_bf16(
                a[mt], b[nt], acc2[mt][nt], 0, 0, 0);
      }
    }

    // -- GEMM1(cc): H chunk = relu(X x W1[:, cc*128:+128]) --
    int hbase = cc * 128 + wid * 32;
    f32x4 acc1[2][4];
#pragma unroll
    for (int mt = 0; mt < 2; ++mt) {
      const float4 bb = *(const float4*)(&b1v[hbase + mt * 16 + quad * 4]);
#pragma unroll
      for (int nt = 0; nt < 4; ++nt) {
        acc1[mt][nt][0] = bb.x; acc1[mt][nt][1] = bb.y;
        acc1[mt][nt][2] = bb.z; acc1[mt][nt][3] = bb.w;
      }
    }
#pragma unroll
    for (int kk = 0; kk < 8; ++kk) {
      int kb = kk * 64 + quad * 16;  // byte offset within 512-B K row
      bf16x8 a[2], b[4];
#pragma unroll
      for (int mt = 0; mt < 2; ++mt)
        a[mt] = *(const bf16x8*)(W1Tc + (hbase + mt * 16 + l16) * 512 + kb);
#pragma unroll
      for (int nt = 0; nt < 4; ++nt) {
        int r = nt * 16 + l16;
        b[nt] = *(const bf16x8*)(smem + SWZ(r * 512 + kb, r));
      }
#pragma unroll
      for (int mt = 0; mt < 2; ++mt)
#pragma unroll
        for (int nt = 0; nt < 4; ++nt)
          acc1[mt][nt] = __builtin_amdgcn_mfma_f32_16x16x32_bf16(
              a[mt], b[nt], acc1[mt][nt], 0, 0, 0);
    }
    // -- epilogue(cc): relu -> bf16 -> Hs[cc&1][token][hloc] --
    {
      char* HsW = smem + 32768 + (cc & 1) * 16384;
#pragma unroll
      for (int mt = 0; mt < 2; ++mt)
#pragma unroll
        for (int nt = 0; nt < 4; ++nt) {
          int token = nt * 16 + l16;
          f32x4 v = acc1[mt][nt];
          *(uint2*)(HsW + SWZ(token * 256 + wid * 64 + mt * 32 + quad * 8, token)) =
              make_uint2(cvtpk(fmaxf(v[0], 0.f), fmaxf(v[1], 0.f)),
                         cvtpk(fmaxf(v[2], 0.f), fmaxf(v[3], 0.f)));
        }
    }
    __syncthreads();  // Hs[cc&1] visible; GEMM2(cc-1) reads complete
  }

  // -- GEMM2(3): tail (reads Hs1; red aliases Hs0 -> safe to write psum after) --
  {
    const char* HsR = smem + 32768 + 16384;
#pragma unroll
    for (int k2 = 0; k2 < 4; ++k2) {
      bf16x8 a[4], b[4];
#pragma unroll
      for (int mt = 0; mt < 4; ++mt)
        a[mt] = *(const bf16x8*)(W2Tc + (wid * 64 + mt * 16 + l16) * 1024 +
                                 3 * 256 + k2 * 64 + quad * 16);
#pragma unroll
      for (int nt = 0; nt < 4; ++nt) {
        int r = nt * 16 + l16;
        b[nt] = *(const bf16x8*)(HsR + SWZ(r * 256 + k2 * 64 + quad * 16, r));
      }
#pragma unroll
      for (int mt = 0; mt < 4; ++mt)
#pragma unroll
        for (int nt = 0; nt < 4; ++nt)
          acc2[mt][nt] = __builtin_amdgcn_mfma_f32_16x16x32_bf16(
              a[mt], b[nt], acc2[mt][nt], 0, 0, 0);
    }
  }

  // ---- Phase 2a: per-token sum/sumsq for LayerNorm ----
#pragma unroll
  for (int nt = 0; nt < 4; ++nt) {
    float s = 0.f, sq = 0.f;
#pragma unroll
    for (int mt = 0; mt < 4; ++mt)
#pragma unroll
      for (int r = 0; r < 4; ++r) {
        float v = acc2[mt][nt][r];
        s += v; sq += v * v;
      }
    s += __shfl_xor(s, 16, 64); sq += __shfl_xor(sq, 16, 64);
    s += __shfl_xor(s, 32, 64); sq += __shfl_xor(sq, 32, 64);
    if (quad == 0) {
      psum[wid * 64 + nt * 16 + l16] = s;
      psumsq[wid * 64 + nt * 16 + l16] = sq;
    }
  }
  __syncthreads();
  if (tid < 64) {
    float s = psum[tid] + psum[64 + tid] + psum[128 + tid] + psum[192 + tid];
    float sq = psumsq[tid] + psumsq[64 + tid] + psumsq[128 + tid] + psumsq[192 + tid];
    float mu = s * (1.f / 256.f);
    float var = sq * (1.f / 256.f) - mu * mu;
    muS[tid] = mu;
    rstdS[tid] = rsqrtf(var + 1e-5f);
  }
  __syncthreads();

  // ---- Phase 2b: normalize in-register, write feats bf16 over Xs, fsq ----
  {
    float4 g[4], be[4];
#pragma unroll
    for (int mt = 0; mt < 4; ++mt) {
      g[mt]  = *(const float4*)(&gammav[wid * 64 + mt * 16 + quad * 4]);
      be[mt] = *(const float4*)(&betav[wid * 64 + mt * 16 + quad * 4]);
    }
#pragma unroll
    for (int nt = 0; nt < 4; ++nt) {
      int token = nt * 16 + l16;
      float mu = muS[token], rs = rstdS[token];
      float fs = 0.f;
#pragma unroll
      for (int mt = 0; mt < 4; ++mt) {
        float y0 = (acc2[mt][nt][0] - mu) * rs * g[mt].x + be[mt].x;
        float y1 = (acc2[mt][nt][1] - mu) * rs * g[mt].y + be[mt].y;
        float y2 = (acc2[mt][nt][2] - mu) * rs * g[mt].z + be[mt].z;
        float y3 = (acc2[mt][nt][3] - mu) * rs * g[mt].w + be[mt].w;
        fs += y0 * y0 + y1 * y1 + y2 * y2 + y3 * y3;
        *(uint2*)(smem + SWZ(token * 512 + wid * 128 + mt * 32 + quad * 8, token)) =
            make_uint2(cvtpk(y0, y1), cvtpk(y2, y3));
      }
      fs += __shfl_xor(fs, 16, 64);
      fs += __shfl_xor(fs, 32, 64);
      if (quad == 0) fsqp[wid * 64 + token] = fs;
    }
  }
  __syncthreads();
  if (tid < 64)
    fsqS[tid] = fsqp[tid] + fsqp[64 + tid] + fsqp[128 + tid] + fsqp[192 + tid];
  __syncthreads();

  // ---- Phase 3: dots GEMM: this wave's 16 tokens vs 64 (padded) memory rows ----
  f32x4 acc3[4];
#pragma unroll
  for (int nt = 0; nt < 4; ++nt) {
    acc3[nt][0] = 0.f; acc3[nt][1] = 0.f; acc3[nt][2] = 0.f; acc3[nt][3] = 0.f;
  }
#pragma unroll
  for (int kk = 0; kk < 8; ++kk) {
    int kb = kk * 64 + quad * 16;
    int ar = wid * 16 + l16;
    bf16x8 a = *(const bf16x8*)(smem + SWZ(ar * 512 + kb, ar));
    int k0 = kk * 32 + quad * 8;
#pragma unroll
    for (int nt = 0; nt < 4; ++nt) {
      bf16x8 b = *(const bf16x8*)(memB + (nt * 16 + l16) * 256 + k0);
      acc3[nt] = __builtin_amdgcn_mfma_f32_16x16x32_bf16(a, b, acc3[nt], 0, 0, 0);
    }
  }
  // distS aliases Xs: every wave must be done with its feats reads above.
  __syncthreads();
  {
    float4 fsq4 = *(const float4*)(&fsqS[wid * 16 + quad * 4]);
#pragma unroll
    for (int nt = 0; nt < 4; ++nt) {
      int col = nt * 16 + l16;
      float mq = msq[col];
#pragma unroll
      for (int r = 0; r < 4; ++r) {
        float fv = (r == 0) ? fsq4.x : (r == 1) ? fsq4.y : (r == 2) ? fsq4.z : fsq4.w;
        float d2 = fv + mq - 2.f * acc3[nt][r];
        float d = sqrtf(fmaxf(d2, 0.f));
        int row = wid * 16 + quad * 4 + r;
        if (col < 50) distS[row * DPitch + col] = d;
      }
    }
  }
  __syncthreads();

  // ---- Phase 4: top-5 smallest of 50, mean, sigmoid ----
  if (tid < 64) {
    float b0 = 1e30f, b1 = 1e30f, b2 = 1e30f, b3 = 1e30f, b4 = 1e30f;
    const float* dr = &distS[tid * DPitch];
    for (int j = 0; j < 50; ++j) {
      float v = dr[j];
      b4 = fminf(b4, v);
      float t;
      if (b4 < b3) { t = b3; b3 = b4; b4 = t; }
      if (b3 < b2) { t = b2; b2 = b3; b3 = t; }
      if (b2 < b1) { t = b1; b1 = b2; b2 = t; }
      if (b1 < b0) { t = b0; b0 = b1; b1 = t; }
    }
    float avg = (b0 + b1 + b2 + b3 + b4) * 0.2f;
    float sarg = avg - 1.f;
    out[blockIdx.x * 64 + tid] = 1.f / (1.f + __expf(-sarg));
  }
}

// ---------------- launch ----------------
extern "C" void kernel_launch(void* const* d_in, const int* in_sizes, int n_in,
                              void* d_out, int out_size, void* d_ws, size_t ws_size,
                              hipStream_t stream) {
  const float* X   = (const float*)d_in[0];  // [8*8192][256]
  const float* mem = (const float*)d_in[1];  // [50][256]
  const float* W1  = (const float*)d_in[2];  // [256][512]
  const float* b1  = (const float*)d_in[3];  // [512]
  const float* W2  = (const float*)d_in[4];  // [512][256]
  const float* b2  = (const float*)d_in[5];  // [256]
  const float* g   = (const float*)d_in[6];  // [256]
  const float* be  = (const float*)d_in[7];  // [256]
  float* out = (float*)d_out;                // [65536]

  unsigned short* W1T  = (unsigned short*)d_ws;   // [512][256] bf16
  unsigned short* W2T  = W1T + 131072;            // [256][512] bf16
  unsigned short* memB = W2T + 131072;            // [64][256] bf16
  float* msq = (float*)(memB + 16384);            // [64] fp32

  prep_weights<<<1089, 256, 0, stream>>>(W1, W2, mem, W1T, W2T, memB, msq);
  fused_main<<<1024, 256, 0, stream>>>(X, b1, b2, g, be, W1T, W2T, memB, msq, out);
}